// Round 6
// baseline (463.167 us; speedup 1.0000x reference)
//
#include <hip/hip_runtime.h>

typedef unsigned short u16;
typedef __attribute__((ext_vector_type(8))) short frag8;
typedef __attribute__((ext_vector_type(4))) float f32x4;

static constexpr int C = 768;
static constexpr int F3 = 2304;      // 3*C
static constexpr int MROWS = 32768;  // B*T*H*W
static constexpr float LNEPS = 1e-5f;

__device__ __forceinline__ float bfu2f(u16 u){
  union { unsigned u; float f; } x; x.u = (unsigned)u << 16; return x.f;
}
__device__ __forceinline__ u16 f2bfu(float f){
  union { float f; unsigned u; } x; x.f = f;
  unsigned r = x.u + 0x7fffu + ((x.u >> 16) & 1u);   // RNE bf16
  return (u16)(r >> 16);
}

__device__ __forceinline__ void gload16(const void* g, void* l){
  __builtin_amdgcn_global_load_lds(
      (const __attribute__((address_space(1))) void*)g,
      (__attribute__((address_space(3))) void*)l, 16, 0, 0);
}

// ---------------- fp32 -> bf16 weight conversion ----------------
__global__ __launch_bounds__(256) void cvt_bf16(const float* __restrict__ src,
                                                u16* __restrict__ dst, int n){
  int i = blockIdx.x * 256 + threadIdx.x;
  if (i < n) dst[i] = f2bfu(src[i]);
}

// ---------------- LN1: fp32 x -> bf16 y ----------------
__global__ __launch_bounds__(256) void ln1_kernel(const float* __restrict__ x,
    const float* __restrict__ w, const float* __restrict__ b, u16* __restrict__ y){
  const int lane = threadIdx.x & 63, wid = threadIdx.x >> 6;
  const size_t row = (size_t)blockIdx.x * 4 + wid;
  const float4* xr = reinterpret_cast<const float4*>(x + row * C);
  float v[12];
  #pragma unroll
  for (int j = 0; j < 3; j++){
    float4 t = xr[lane + j*64];
    v[j*4+0]=t.x; v[j*4+1]=t.y; v[j*4+2]=t.z; v[j*4+3]=t.w;
  }
  float s = 0.f, ss = 0.f;
  #pragma unroll
  for (int j = 0; j < 12; j++){ s += v[j]; ss += v[j]*v[j]; }
  #pragma unroll
  for (int o = 32; o; o >>= 1){ s += __shfl_xor(s, o, 64); ss += __shfl_xor(ss, o, 64); }
  const float mu = s * (1.f/768.f);
  const float rs = rsqrtf(ss*(1.f/768.f) - mu*mu + LNEPS);
  ushort4* yr = reinterpret_cast<ushort4*>(y + row * C);
  const float4* wv = reinterpret_cast<const float4*>(w);
  const float4* bv = reinterpret_cast<const float4*>(b);
  #pragma unroll
  for (int j = 0; j < 3; j++){
    float4 wj = wv[lane + j*64], bj = bv[lane + j*64];
    ushort4 o4;
    o4.x = f2bfu((v[j*4+0]-mu)*rs*wj.x + bj.x);
    o4.y = f2bfu((v[j*4+1]-mu)*rs*wj.y + bj.y);
    o4.z = f2bfu((v[j*4+2]-mu)*rs*wj.z + bj.z);
    o4.w = f2bfu((v[j*4+3]-mu)*rs*wj.w + bj.w);
    yr[lane + j*64] = o4;
  }
}

// ---------------- GEMM: C[m,n] = sum_k A[m,k]*B[n,k]  (B^T layout) ----------------
// BM=256, BN=256, BK=32, 24 K-tiles. 512 threads, 8 waves 2M x 4N,
// wave tile 128x64 (FLOP/LDS-byte = 42.7 vs 32 at 64x64 -> LDS no longer the floor).
// A: staged in LDS ring-4 x 16KB (sigma subtiles, R3-verified conflict-free +
//    coalesced). B: weights are L2-resident (<=3.5MB) -> loaded DIRECTLY from
//    global into registers (per-lane gather, 16 rows x 64B full lines),
//    double-buffered one tile ahead. No B staging writes, no B LDS reads.
// Sync per tile: barrier; loadB(t+1); stageA(t+3); ds_read A(t); vmcnt(6)
// leaves exactly {B(t+1)x4, A(t+3)x2} outstanding (in-order retirement) ->
// A(t),B(t) ready with >=1 tile (~1900cy) latency cover. Ring slot (t+3)&3 is
// overwritten only after the barrier that follows its last reads (lgkm drained
// before MFMAs) -> race-free (same argument as R4/R5, absmax-verified).
// MFMA operands swapped (acc quad = 4 consecutive n -> vectorized stores).
// MODE 0: out = bf16(acc + bias)            (qkv projection)
// MODE 1: out = fp32(acc + bias + resid)    (out projection + residual)
template<int MODE>
__global__ __launch_bounds__(512, 2) void gemm_bt(
    const u16* __restrict__ A, const u16* __restrict__ Bw,
    const float* __restrict__ bias, const float* __restrict__ resid,
    void* __restrict__ Cout, int Ndim, int K)
{
  __shared__ __align__(16) char lds[65536];     // ring4 x 16KB (A only)
  const int tid = threadIdx.x;
  const int lane = tid & 63, wid = tid >> 6;
  const int wm = wid >> 2, wn = wid & 3;        // 2 x 4 wave grid
  const int ntn = Ndim >> 8;
  const int cpx = (int)gridDim.x >> 3;          // bijective XCD swizzle (grid%8==0)
  const int wg = ((int)blockIdx.x & 7) * cpx + ((int)blockIdx.x >> 3);
  const int bm = wg / ntn, bn = wg % ntn;
  const int m0 = bm << 8, n0 = bn << 8;

  // A staging source decode (sigma^-1): lane -> (row rr, kchunk qq) of a subtile
  const int rp = lane >> 2;
  const int rr = rp ^ ((rp >> 2) & 1);
  const int qq = (lane & 3) ^ (rr & 3);
  const u16* aS = A + (size_t)(m0 + wid*32 + rr) * K + qq*8;
  const size_t rstep = 16 * (size_t)K;

  // fragment read offset within subtile (sigma of (fr,kq)), bytes
  const int fr = lane & 15, kq = lane >> 4;
  const int sig16 = (((fr ^ ((fr >> 2) & 1)) << 2) | (kq ^ (fr & 3))) * 16;

  // B gather pointers: lane reads row (n0+wn*64+nf*16+fr), k-chunk kq
  const u16* bP0 = Bw + (size_t)(n0 + wn*64 +  0 + fr) * K + kq*8;
  const u16* bP1 = Bw + (size_t)(n0 + wn*64 + 16 + fr) * K + kq*8;
  const u16* bP2 = Bw + (size_t)(n0 + wn*64 + 32 + fr) * K + kq*8;
  const u16* bP3 = Bw + (size_t)(n0 + wn*64 + 48 + fr) * K + kq*8;

  f32x4 acc[8][4] = {};   // [mf][nf], wave tile 128x64

  auto stageA = [&](int st){
    char* lb = lds + (st & 3)*16384 + wid*2048;
    const u16* ga = aS + st*32;
    gload16(ga,         lb);
    gload16(ga + rstep, lb + 1024);
  };
  auto loadB = [&](int st, frag8 (&d)[4]){
    const int o = st*32;
    d[0] = *reinterpret_cast<const frag8*>(bP0 + o);
    d[1] = *reinterpret_cast<const frag8*>(bP1 + o);
    d[2] = *reinterpret_cast<const frag8*>(bP2 + o);
    d[3] = *reinterpret_cast<const frag8*>(bP3 + o);
  };

  frag8 bA_[4], bB_[4];                     // named double-buffers (rule #20)
  auto tileStep = [&](int t, frag8 (&bc)[4], frag8 (&bn)[4]){
    __builtin_amdgcn_s_barrier();
    asm volatile("" ::: "memory");
    int tb = t + 1; if (tb >= 24) tb = 0;   // wrapped tail keeps vmcnt uniform
    loadB(tb, bn);
    int ta = t + 3; if (ta >= 24) ta -= 24;
    stageA(ta);
    const char* pa = lds + (t & 3)*16384 + (wm*8)*1024 + sig16;
    frag8 af[8];
    #pragma unroll
    for (int mf = 0; mf < 8; mf++) af[mf] = *reinterpret_cast<const frag8*>(pa + mf*1024);
    asm volatile("s_waitcnt vmcnt(6)" ::: "memory");
    __builtin_amdgcn_sched_barrier(0);
    __builtin_amdgcn_s_setprio(1);
    #pragma unroll
    for (int mf = 0; mf < 8; mf++)
      #pragma unroll
      for (int nf = 0; nf < 4; nf++)
        acc[mf][nf] = __builtin_amdgcn_mfma_f32_16x16x32_bf16(bc[nf], af[mf], acc[mf][nf], 0, 0, 0);
    __builtin_amdgcn_s_setprio(0);
  };

  stageA(0); stageA(1); stageA(2);          // 6 gload_lds in flight
  loadB(0, bA_);                            // +4 reg loads

  for (int t = 0; t < 24; t += 2){
    tileStep(t,     bA_, bB_);
    tileStep(t + 1, bB_, bA_);
  }

  // epilogue (swapped layout): m = lane&15, n-quad = (lane>>4)*4
  const int em = fr, en = kq * 4;
  float4 bb[4];
  #pragma unroll
  for (int nf = 0; nf < 4; nf++)
    bb[nf] = *reinterpret_cast<const float4*>(bias + n0 + wn*64 + nf*16 + en);

  #pragma unroll
  for (int mf = 0; mf < 8; mf++){
    const size_t m = (size_t)(m0 + wm*128 + mf*16 + em);
    #pragma unroll
    for (int nf = 0; nf < 4; nf++){
      const int n = n0 + wn*64 + nf*16 + en;
      if (MODE == 0){
        ushort4 o4;
        o4.x = f2bfu(acc[mf][nf][0] + bb[nf].x);
        o4.y = f2bfu(acc[mf][nf][1] + bb[nf].y);
        o4.z = f2bfu(acc[mf][nf][2] + bb[nf].z);
        o4.w = f2bfu(acc[mf][nf][3] + bb[nf].w);
        *reinterpret_cast<ushort4*>((u16*)Cout + m * Ndim + n) = o4;
      } else {
        const float4 rr4 = *reinterpret_cast<const float4*>(resid + m * Ndim + n);
        float4 o4;
        o4.x = acc[mf][nf][0] + bb[nf].x + rr4.x;
        o4.y = acc[mf][nf][1] + bb[nf].y + rr4.y;
        o4.z = acc[mf][nf][2] + bb[nf].z + rr4.z;
        o4.w = acc[mf][nf][3] + bb[nf].w + rr4.w;
        *reinterpret_cast<float4*>((float*)Cout + m * Ndim + n) = o4;
      }
    }
  }
}

// ---------------- attention over T=16, one wave per (b,h,w,head) ----------------
// qkv row layout per head n: f = n*192 + [0:64)=q [64:128)=k [128:192)=v
// output o (16x64) overwrites the v-slots (already staged to LDS before write).
__global__ __launch_bounds__(64) void attn_kernel(u16* __restrict__ qkv){
  __shared__ __align__(16) u16 sq[16][72];
  __shared__ __align__(16) u16 sk[16][72];
  __shared__ __align__(16) u16 sv[16][72];
  __shared__ float sp[16][17];
  const int lane = threadIdx.x;
  int bid = blockIdx.x;
  const int n = bid % 12; bid /= 12;
  const int w = bid % 32; bid /= 32;
  const int h = bid % 32; const int b = bid / 32;
  u16* base = qkv + ((size_t)(b*16384 + h*32 + w)) * F3 + n * 192;
  const size_t tstride = (size_t)1024 * F3;   // t-step = 1024 rows

  #pragma unroll
  for (int i = 0; i < 6; i++){
    const int e8 = lane + i*64;
    const int t = e8 / 24, ck = e8 % 24;
    uint4 val = *reinterpret_cast<const uint4*>(base + (size_t)t*tstride + ck*8);
    u16* dst = (ck < 8) ? &sq[t][ck*8] : (ck < 16) ? &sk[t][(ck-8)*8] : &sv[t][(ck-16)*8];
    *reinterpret_cast<uint4*>(dst) = val;
  }
  __syncthreads();

  const int g = lane >> 4, sj = lane & 15;
  float accv[4] = {0.f, 0.f, 0.f, 0.f};
  #pragma unroll
  for (int dc = 0; dc < 8; dc++){
    union { uint4 u; u16 s[8]; } kc;
    kc.u = *reinterpret_cast<const uint4*>(&sk[sj][dc*8]);
    #pragma unroll
    for (int i = 0; i < 4; i++){
      union { uint4 u; u16 s[8]; } qc;
      qc.u = *reinterpret_cast<const uint4*>(&sq[g + i*4][dc*8]);
      #pragma unroll
      for (int e = 0; e < 8; e++)
        accv[i] += bfu2f(qc.s[e]) * bfu2f(kc.s[e]);
    }
  }
  #pragma unroll
  for (int i = 0; i < 4; i++){
    float sc = accv[i] * 0.125f;
    float mx = sc;
    #pragma unroll
    for (int o = 1; o < 16; o <<= 1) mx = fmaxf(mx, __shfl_xor(mx, o, 16));
    float p = __expf(sc - mx);
    float sm = p;
    #pragma unroll
    for (int o = 1; o < 16; o <<= 1) sm += __shfl_xor(sm, o, 16);
    sp[g + i*4][sj] = p / sm;
  }
  __syncthreads();

  #pragma unroll
  for (int t = 0; t < 16; t++){
    float o = 0.f;
    #pragma unroll
    for (int s = 0; s < 16; s++) o += sp[t][s] * bfu2f(sv[s][lane]);
    base[(size_t)t*tstride + 128 + lane] = f2bfu(o);
  }
}

// ---------------- LN2: reads attention output from v-slots of qkv ----------------
__global__ __launch_bounds__(256) void ln2_kernel(const u16* __restrict__ qkv,
    const float* __restrict__ w, const float* __restrict__ b, u16* __restrict__ y2){
  const int lane = threadIdx.x & 63, wid = threadIdx.x >> 6;
  const size_t row = (size_t)blockIdx.x * 4 + wid;
  const u16* src = qkv + row * F3 + 128;
  float v[12];
  #pragma unroll
  for (int j = 0; j < 12; j++) v[j] = bfu2f(src[j*192 + lane]);   // c = j*64+lane
  float s = 0.f, ss = 0.f;
  #pragma unroll
  for (int j = 0; j < 12; j++){ s += v[j]; ss += v[j]*v[j]; }
  #pragma unroll
  for (int o = 32; o; o >>= 1){ s += __shfl_xor(s, o, 64); ss += __shfl_xor(ss, o, 64); }
  const float mu = s * (1.f/768.f);
  const float rs = rsqrtf(ss*(1.f/768.f) - mu*mu + LNEPS);
  #pragma unroll
  for (int j = 0; j < 12; j++){
    const int c = j*64 + lane;
    y2[row * C + c] = f2bfu((v[j]-mu)*rs*w[c] + b[c]);
  }
}

extern "C" void kernel_launch(void* const* d_in, const int* in_sizes, int n_in,
                              void* d_out, int out_size, void* d_ws, size_t ws_size,
                              hipStream_t stream){
  const float* x    = (const float*)d_in[0];
  const float* ln1w = (const float*)d_in[1];
  const float* ln1b = (const float*)d_in[2];
  const float* Wqkv = (const float*)d_in[3];
  const float* bqkv = (const float*)d_in[4];
  const float* ln2w = (const float*)d_in[5];
  const float* ln2b = (const float*)d_in[6];
  const float* Wout = (const float*)d_in[7];
  const float* bout = (const float*)d_in[8];
  float* out = (float*)d_out;

  char* ws = (char*)d_ws;
  u16* qkv = (u16*)ws;                       // 32768*2304*2 = 150,994,944 B
  u16* y   = (u16*)(ws + 150994944);         // 32768*768*2  =  50,331,648 B (y1, then y2)
  u16* wq  = (u16*)(ws + 201326592);         // 2304*768*2   =   3,538,944 B
  u16* wo  = (u16*)(ws + 204865536);         // 768*768*2    =   1,179,648 B  (total 206,045,184)

  cvt_bf16<<<(F3*C + 255)/256, 256, 0, stream>>>(Wqkv, wq, F3*C);
  cvt_bf16<<<(C*C + 255)/256, 256, 0, stream>>>(Wout, wo, C*C);
  ln1_kernel<<<MROWS/4, 256, 0, stream>>>(x, ln1w, ln1b, y);
  gemm_bt<0><<<(MROWS/256)*(F3/256), 512, 0, stream>>>(y, wq, bqkv, nullptr, qkv, F3, C);
  attn_kernel<<<2*32*32*12, 64, 0, stream>>>(qkv);
  ln2_kernel<<<MROWS/4, 256, 0, stream>>>(qkv, ln2w, ln2b, y);
  gemm_bt<1><<<(MROWS/256)*(C/256), 512, 0, stream>>>(y, wo, bout, x, out, C, C);
}

// Round 7
// 387.089 us; speedup vs baseline: 1.1965x; 1.1965x over previous
//
#include <hip/hip_runtime.h>

typedef unsigned short u16;
typedef __attribute__((ext_vector_type(8))) short frag8;
typedef __attribute__((ext_vector_type(4))) float f32x4;

static constexpr int C = 768;
static constexpr int F3 = 2304;      // 3*C
static constexpr int MROWS = 32768;  // B*T*H*W
static constexpr float LNEPS = 1e-5f;

__device__ __forceinline__ float bfu2f(u16 u){
  union { unsigned u; float f; } x; x.u = (unsigned)u << 16; return x.f;
}
__device__ __forceinline__ u16 f2bfu(float f){
  union { float f; unsigned u; } x; x.f = f;
  unsigned r = x.u + 0x7fffu + ((x.u >> 16) & 1u);   // RNE bf16
  return (u16)(r >> 16);
}

__device__ __forceinline__ void gload16(const void* g, void* l){
  __builtin_amdgcn_global_load_lds(
      (const __attribute__((address_space(1))) void*)g,
      (__attribute__((address_space(3))) void*)l, 16, 0, 0);
}

// ---------------- fp32 -> bf16 weight conversion ----------------
__global__ __launch_bounds__(256) void cvt_bf16(const float* __restrict__ src,
                                                u16* __restrict__ dst, int n){
  int i = blockIdx.x * 256 + threadIdx.x;
  if (i < n) dst[i] = f2bfu(src[i]);
}

// ---------------- LN1: fp32 x -> bf16 y ----------------
__global__ __launch_bounds__(256) void ln1_kernel(const float* __restrict__ x,
    const float* __restrict__ w, const float* __restrict__ b, u16* __restrict__ y){
  const int lane = threadIdx.x & 63, wid = threadIdx.x >> 6;
  const size_t row = (size_t)blockIdx.x * 4 + wid;
  const float4* xr = reinterpret_cast<const float4*>(x + row * C);
  float v[12];
  #pragma unroll
  for (int j = 0; j < 3; j++){
    float4 t = xr[lane + j*64];
    v[j*4+0]=t.x; v[j*4+1]=t.y; v[j*4+2]=t.z; v[j*4+3]=t.w;
  }
  float s = 0.f, ss = 0.f;
  #pragma unroll
  for (int j = 0; j < 12; j++){ s += v[j]; ss += v[j]*v[j]; }
  #pragma unroll
  for (int o = 32; o; o >>= 1){ s += __shfl_xor(s, o, 64); ss += __shfl_xor(ss, o, 64); }
  const float mu = s * (1.f/768.f);
  const float rs = rsqrtf(ss*(1.f/768.f) - mu*mu + LNEPS);
  ushort4* yr = reinterpret_cast<ushort4*>(y + row * C);
  const float4* wv = reinterpret_cast<const float4*>(w);
  const float4* bv = reinterpret_cast<const float4*>(b);
  #pragma unroll
  for (int j = 0; j < 3; j++){
    float4 wj = wv[lane + j*64], bj = bv[lane + j*64];
    ushort4 o4;
    o4.x = f2bfu((v[j*4+0]-mu)*rs*wj.x + bj.x);
    o4.y = f2bfu((v[j*4+1]-mu)*rs*wj.y + bj.y);
    o4.z = f2bfu((v[j*4+2]-mu)*rs*wj.z + bj.z);
    o4.w = f2bfu((v[j*4+3]-mu)*rs*wj.w + bj.w);
    yr[lane + j*64] = o4;
  }
}

// ---------------- GEMM: C[m,n] = sum_k A[m,k]*B[n,k]  (B^T layout) ----------------
// 8-phase-style schedule (T3+T4), derived for K=768:
// BM=BN=256, BK=32, 24 K-tiles, 48 phases (2/K-tile: q0=mf0-3, q1=mf4-7; 16 MFMA each).
// LDS ring-4 x 32KB (A 16KB + B 16KB per K-tile) = 128KB. One half (A or B of a
// future tile, 2 gload_lds/thread) staged per phase: q0 stages B(t+2), q1 stages
// A(t+3) (stage lead 5 phases). Counted vmcnt(6) + lgkm(0) BEFORE each barrier:
//   - phase P's vmcnt retires halves <= h_{P+2}; phase P+1's ds_reads need
//     exactly h_{<=P+2}  -> read-after-write safe, loads span 5 phases.
//   - ring-4: each stage overwrites a slot last read >=2 barriers earlier, and
//     lgkm(0) pre-barrier drains those reads -> write-after-read safe.
//   - wrapped tail stages (t+2/t+3 -> 0..2) keep vmcnt uniform; slots match (24%4==0).
// Subtile = 16r x 32k sigma-swizzled (R3-verified): coalesced 64B global segments
// per lane-quad AND conflict-free ds_read_b128.
// MFMA operands swapped: acc quad = 4 consecutive n -> vectorized direct stores.
// MODE 0: out = bf16(acc + bias)            (qkv projection)
// MODE 1: out = fp32(acc + bias + resid)    (out projection + residual)
template<int MODE>
__global__ __launch_bounds__(512, 2) void gemm_bt(
    const u16* __restrict__ A, const u16* __restrict__ Bw,
    const float* __restrict__ bias, const float* __restrict__ resid,
    void* __restrict__ Cout, int Ndim, int K)
{
  __shared__ __align__(16) char lds[131072];
  const int tid = threadIdx.x;
  const int lane = tid & 63, wid = tid >> 6;
  const int wm = wid >> 2, wn = wid & 3;        // 2 x 4 wave grid
  const int ntn = Ndim >> 8;
  const int cpx = (int)gridDim.x >> 3;          // bijective XCD swizzle (grid%8==0)
  const int wg = ((int)blockIdx.x & 7) * cpx + ((int)blockIdx.x >> 3);
  const int bm = wg / ntn, bn = wg % ntn;
  const int m0 = bm << 8, n0 = bn << 8;

  // staging source decode (sigma^-1): lane -> (row rr, kchunk qq) of a subtile
  const int rp = lane >> 2;
  const int rr = rp ^ ((rp >> 2) & 1);
  const int qq = (lane & 3) ^ (rr & 3);
  const u16* aS = A  + (size_t)(m0 + wid*16 + rr) * K + qq*8;
  const u16* bS = Bw + (size_t)(n0 + wid*16 + rr) * K + qq*8;
  const size_t half128 = 128 * (size_t)K;

  // fragment read offset within subtile (sigma of (fr,kq)), bytes
  const int fr = lane & 15, kq = lane >> 4;
  const int sig16 = (((fr ^ ((fr >> 2) & 1)) << 2) | (kq ^ (fr & 3))) * 16;

  f32x4 acc[8][4] = {};   // [mf][nf], wave tile 128x64

  // stage A-half / B-half of K-tile ts into ring slot ts&3 (wave covers
  // subtiles wid and wid+8: rows wid*16.. and 128+wid*16..)
  auto stA = [&](int ts){
    char* lb = lds + (ts & 3)*32768;
    gload16(aS + ts*32,           lb + wid*1024);
    gload16(aS + ts*32 + half128, lb + (8+wid)*1024);
  };
  auto stB = [&](int ts){
    char* lb = lds + (ts & 3)*32768 + 16384;
    gload16(bS + ts*32,           lb + wid*1024);
    gload16(bS + ts*32 + half128, lb + (8+wid)*1024);
  };

  // prologue: halves A0,B0,A1,B1,A2 (10 loads); vmcnt(6) retires A0,B0
  stA(0); stB(0); stA(1); stB(1); stA(2);
  asm volatile("s_waitcnt vmcnt(6)" ::: "memory");
  __builtin_amdgcn_s_barrier();

  for (int t = 0; t < 24; ++t){
    const char* base = lds + (t & 3)*32768;
    int tb = t + 2; if (tb >= 24) tb -= 24;
    int ta = t + 3; if (ta >= 24) ta -= 24;
    frag8 af[4], bf[4], ag[4];

    // ---------- phase q0: read A mf0-3 + B nf0-3, stage B(t+2) ----------
    #pragma unroll
    for (int mf = 0; mf < 4; mf++)
      af[mf] = *reinterpret_cast<const frag8*>(base + (wm*8+mf)*1024 + sig16);
    #pragma unroll
    for (int nf = 0; nf < 4; nf++)
      bf[nf] = *reinterpret_cast<const frag8*>(base + 16384 + (wn*4+nf)*1024 + sig16);
    stB(tb);
    asm volatile("s_waitcnt vmcnt(6)" ::: "memory");
    asm volatile("s_waitcnt lgkmcnt(0)" ::: "memory");
    __builtin_amdgcn_sched_barrier(0);
    __builtin_amdgcn_s_barrier();
    __builtin_amdgcn_s_setprio(1);
    #pragma unroll
    for (int mf = 0; mf < 4; mf++)
      #pragma unroll
      for (int nf = 0; nf < 4; nf++)
        acc[mf][nf] = __builtin_amdgcn_mfma_f32_16x16x32_bf16(bf[nf], af[mf], acc[mf][nf], 0, 0, 0);
    __builtin_amdgcn_s_setprio(0);

    // ---------- phase q1: read A mf4-7, stage A(t+3) ----------
    #pragma unroll
    for (int mf = 0; mf < 4; mf++)
      ag[mf] = *reinterpret_cast<const frag8*>(base + (wm*8+4+mf)*1024 + sig16);
    stA(ta);
    asm volatile("s_waitcnt vmcnt(6)" ::: "memory");
    asm volatile("s_waitcnt lgkmcnt(0)" ::: "memory");
    __builtin_amdgcn_sched_barrier(0);
    __builtin_amdgcn_s_barrier();
    __builtin_amdgcn_s_setprio(1);
    #pragma unroll
    for (int mf = 0; mf < 4; mf++)
      #pragma unroll
      for (int nf = 0; nf < 4; nf++)
        acc[4+mf][nf] = __builtin_amdgcn_mfma_f32_16x16x32_bf16(bf[nf], ag[mf], acc[4+mf][nf], 0, 0, 0);
    __builtin_amdgcn_s_setprio(0);
  }
  asm volatile("s_waitcnt vmcnt(0)" ::: "memory");   // drain wrapped tail stages

  // epilogue (swapped layout): m = lane&15 (+16mf+128wm), n-quad = (lane>>4)*4 (+16nf+64wn)
  const int em = fr, en = kq * 4;
  float4 bb[4];
  #pragma unroll
  for (int nf = 0; nf < 4; nf++)
    bb[nf] = *reinterpret_cast<const float4*>(bias + n0 + wn*64 + nf*16 + en);

  #pragma unroll
  for (int mf = 0; mf < 8; mf++){
    const size_t m = (size_t)(m0 + wm*128 + mf*16 + em);
    #pragma unroll
    for (int nf = 0; nf < 4; nf++){
      const int n = n0 + wn*64 + nf*16 + en;
      if (MODE == 0){
        ushort4 o4;
        o4.x = f2bfu(acc[mf][nf][0] + bb[nf].x);
        o4.y = f2bfu(acc[mf][nf][1] + bb[nf].y);
        o4.z = f2bfu(acc[mf][nf][2] + bb[nf].z);
        o4.w = f2bfu(acc[mf][nf][3] + bb[nf].w);
        *reinterpret_cast<ushort4*>((u16*)Cout + m * Ndim + n) = o4;
      } else {
        const float4 rr4 = *reinterpret_cast<const float4*>(resid + m * Ndim + n);
        float4 o4;
        o4.x = acc[mf][nf][0] + bb[nf].x + rr4.x;
        o4.y = acc[mf][nf][1] + bb[nf].y + rr4.y;
        o4.z = acc[mf][nf][2] + bb[nf].z + rr4.z;
        o4.w = acc[mf][nf][3] + bb[nf].w + rr4.w;
        *reinterpret_cast<float4*>((float*)Cout + m * Ndim + n) = o4;
      }
    }
  }
}

// ---------------- attention over T=16, one wave per (b,h,w,head) ----------------
// qkv row layout per head n: f = n*192 + [0:64)=q [64:128)=k [128:192)=v
// output o (16x64) overwrites the v-slots (already staged to LDS before write).
__global__ __launch_bounds__(64) void attn_kernel(u16* __restrict__ qkv){
  __shared__ __align__(16) u16 sq[16][72];
  __shared__ __align__(16) u16 sk[16][72];
  __shared__ __align__(16) u16 sv[16][72];
  __shared__ float sp[16][17];
  const int lane = threadIdx.x;
  int bid = blockIdx.x;
  const int n = bid % 12; bid /= 12;
  const int w = bid % 32; bid /= 32;
  const int h = bid % 32; const int b = bid / 32;
  u16* base = qkv + ((size_t)(b*16384 + h*32 + w)) * F3 + n * 192;
  const size_t tstride = (size_t)1024 * F3;   // t-step = 1024 rows

  #pragma unroll
  for (int i = 0; i < 6; i++){
    const int e8 = lane + i*64;
    const int t = e8 / 24, ck = e8 % 24;
    uint4 val = *reinterpret_cast<const uint4*>(base + (size_t)t*tstride + ck*8);
    u16* dst = (ck < 8) ? &sq[t][ck*8] : (ck < 16) ? &sk[t][(ck-8)*8] : &sv[t][(ck-16)*8];
    *reinterpret_cast<uint4*>(dst) = val;
  }
  __syncthreads();

  const int g = lane >> 4, sj = lane & 15;
  float accv[4] = {0.f, 0.f, 0.f, 0.f};
  #pragma unroll
  for (int dc = 0; dc < 8; dc++){
    union { uint4 u; u16 s[8]; } kc;
    kc.u = *reinterpret_cast<const uint4*>(&sk[sj][dc*8]);
    #pragma unroll
    for (int i = 0; i < 4; i++){
      union { uint4 u; u16 s[8]; } qc;
      qc.u = *reinterpret_cast<const uint4*>(&sq[g + i*4][dc*8]);
      #pragma unroll
      for (int e = 0; e < 8; e++)
        accv[i] += bfu2f(qc.s[e]) * bfu2f(kc.s[e]);
    }
  }
  #pragma unroll
  for (int i = 0; i < 4; i++){
    float sc = accv[i] * 0.125f;
    float mx = sc;
    #pragma unroll
    for (int o = 1; o < 16; o <<= 1) mx = fmaxf(mx, __shfl_xor(mx, o, 16));
    float p = __expf(sc - mx);
    float sm = p;
    #pragma unroll
    for (int o = 1; o < 16; o <<= 1) sm += __shfl_xor(sm, o, 16);
    sp[g + i*4][sj] = p / sm;
  }
  __syncthreads();

  #pragma unroll
  for (int t = 0; t < 16; t++){
    float o = 0.f;
    #pragma unroll
    for (int s = 0; s < 16; s++) o += sp[t][s] * bfu2f(sv[s][lane]);
    base[(size_t)t*tstride + 128 + lane] = f2bfu(o);
  }
}

// ---------------- LN2: reads attention output from v-slots of qkv ----------------
__global__ __launch_bounds__(256) void ln2_kernel(const u16* __restrict__ qkv,
    const float* __restrict__ w, const float* __restrict__ b, u16* __restrict__ y2){
  const int lane = threadIdx.x & 63, wid = threadIdx.x >> 6;
  const size_t row = (size_t)blockIdx.x * 4 + wid;
  const u16* src = qkv + row * F3 + 128;
  float v[12];
  #pragma unroll
  for (int j = 0; j < 12; j++) v[j] = bfu2f(src[j*192 + lane]);   // c = j*64+lane
  float s = 0.f, ss = 0.f;
  #pragma unroll
  for (int j = 0; j < 12; j++){ s += v[j]; ss += v[j]*v[j]; }
  #pragma unroll
  for (int o = 32; o; o >>= 1){ s += __shfl_xor(s, o, 64); ss += __shfl_xor(ss, o, 64); }
  const float mu = s * (1.f/768.f);
  const float rs = rsqrtf(ss*(1.f/768.f) - mu*mu + LNEPS);
  #pragma unroll
  for (int j = 0; j < 12; j++){
    const int c = j*64 + lane;
    y2[row * C + c] = f2bfu((v[j]-mu)*rs*w[c] + b[c]);
  }
}

extern "C" void kernel_launch(void* const* d_in, const int* in_sizes, int n_in,
                              void* d_out, int out_size, void* d_ws, size_t ws_size,
                              hipStream_t stream){
  const float* x    = (const float*)d_in[0];
  const float* ln1w = (const float*)d_in[1];
  const float* ln1b = (const float*)d_in[2];
  const float* Wqkv = (const float*)d_in[3];
  const float* bqkv = (const float*)d_in[4];
  const float* ln2w = (const float*)d_in[5];
  const float* ln2b = (const float*)d_in[6];
  const float* Wout = (const float*)d_in[7];
  const float* bout = (const float*)d_in[8];
  float* out = (float*)d_out;

  char* ws = (char*)d_ws;
  u16* qkv = (u16*)ws;                       // 32768*2304*2 = 150,994,944 B
  u16* y   = (u16*)(ws + 150994944);         // 32768*768*2  =  50,331,648 B (y1, then y2)
  u16* wq  = (u16*)(ws + 201326592);         // 2304*768*2   =   3,538,944 B
  u16* wo  = (u16*)(ws + 204865536);         // 768*768*2    =   1,179,648 B  (total 206,045,184)

  cvt_bf16<<<(F3*C + 255)/256, 256, 0, stream>>>(Wqkv, wq, F3*C);
  cvt_bf16<<<(C*C + 255)/256, 256, 0, stream>>>(Wout, wo, C*C);
  ln1_kernel<<<MROWS/4, 256, 0, stream>>>(x, ln1w, ln1b, y);
  gemm_bt<0><<<(MROWS/256)*(F3/256), 512, 0, stream>>>(y, wq, bqkv, nullptr, qkv, F3, C);
  attn_kernel<<<2*32*32*12, 64, 0, stream>>>(qkv);
  ln2_kernel<<<MROWS/4, 256, 0, stream>>>(qkv, ln2w, ln2b, y);
  gemm_bt<1><<<(MROWS/256)*(C/256), 512, 0, stream>>>(y, wo, bout, x, out, C, C);
}